// Round 1
// baseline (3960.709 us; speedup 1.0000x reference)
//
#include <hip/hip_runtime.h>

#define TPB_CONV 512

// ---------------------------------------------------------------------------
// Kernel 1: fused conv1+pool -> conv2+pool -> conv3+pool, one image per block.
// All intermediates live in LDS. Output: out3[img][p(9)][c(32)]  (p*32+c order)
// ---------------------------------------------------------------------------
__global__ __launch_bounds__(TPB_CONV) void fused_conv_kernel(
    const float* __restrict__ x,
    const float* __restrict__ cw1, const float* __restrict__ cb1,
    const float* __restrict__ cw2, const float* __restrict__ cb2,
    const float* __restrict__ cw3, const float* __restrict__ cb3,
    float* __restrict__ out3)
{
    const int img = blockIdx.x;
    const int tid = threadIdx.x;

    __shared__ float xs1[900];        // 30x30 zero-padded input image
    __shared__ float w1s[288];        // conv1 weights [tap][oc]
    __shared__ float b1s[32], b2s[32], b3s[32];
    __shared__ float xs2[32 * 257];   // conv1 out / conv2 in: [ic][16x16 pad], plane stride 257
    __shared__ float wck[72 * 33];    // conv2/3 weight chunk: [dic*9+tap][oc], stride 33
    __shared__ float xs3[32 * 81];    // conv2 out / conv3 in: [ic][9x9 pad]

    // --- zero LDS (borders stay zero = implicit padding) ---
    for (int i = tid; i < 900;      i += TPB_CONV) xs1[i] = 0.f;
    for (int i = tid; i < 32 * 257; i += TPB_CONV) xs2[i] = 0.f;
    for (int i = tid; i < 32 * 81;  i += TPB_CONV) xs3[i] = 0.f;
    __syncthreads();

    // --- stage input image + conv1 weights ---
    for (int i = tid; i < 784; i += TPB_CONV) {
        int yy = i / 28, xx = i % 28;
        xs1[(yy + 1) * 30 + xx + 1] = x[img * 784 + i];
    }
    for (int i = tid; i < 288; i += TPB_CONV) {
        int oc = i & 31, tap = i >> 5;            // i = tap*32 + oc
        w1s[i] = cw1[oc * 9 + tap];
    }
    if (tid < 32) { b1s[tid] = cb1[tid]; b2s[tid] = cb2[tid]; b3s[tid] = cb3[tid]; }
    __syncthreads();

    // --- conv1 (1->32, 28x28) + relu + pool -> xs2 interior (14x14) ---
    for (int o = tid; o < 32 * 196; o += TPB_CONV) {
        int c = o & 31, p = o >> 5;               // lanes: consecutive c -> broadcast patch reads
        int py = p / 14, px = p % 14;
        int base = (2 * py) * 30 + 2 * px;
        float P[16];
        #pragma unroll
        for (int r = 0; r < 4; r++)
            #pragma unroll
            for (int s = 0; s < 4; s++)
                P[r * 4 + s] = xs1[base + r * 30 + s];
        float a00 = 0.f, a01 = 0.f, a10 = 0.f, a11 = 0.f;
        #pragma unroll
        for (int ky = 0; ky < 3; ky++)
            #pragma unroll
            for (int kx = 0; kx < 3; kx++) {
                float w = w1s[(ky * 3 + kx) * 32 + c];
                a00 = fmaf(P[ky * 4 + kx],           w, a00);
                a01 = fmaf(P[ky * 4 + kx + 1],       w, a01);
                a10 = fmaf(P[(ky + 1) * 4 + kx],     w, a10);
                a11 = fmaf(P[(ky + 1) * 4 + kx + 1], w, a11);
            }
        // relu(max+b) == max(relu(ai+b)) since same bias, relu monotone
        float v = fmaxf(fmaxf(fmaxf(a00, a01), fmaxf(a10, a11)) + b1s[c], 0.f);
        xs2[c * 257 + (py + 1) * 16 + (px + 1)] = v;   // stride 257 -> conflict-free
    }

    // --- conv2 (32->32, 14x14) + relu + pool -> xs3 interior (7x7) ---
    float acc[4][4];
    #pragma unroll
    for (int k = 0; k < 4; k++)
        #pragma unroll
        for (int q = 0; q < 4; q++) acc[k][q] = 0.f;

    for (int ch = 0; ch < 4; ch++) {              // 4 chunks of 8 input channels
        __syncthreads();
        for (int i = tid; i < 2304; i += TPB_CONV) {
            int oc = i / 72, rem = i % 72;        // rem = dic*9 + tap
            wck[rem * 33 + oc] = cw2[oc * 288 + ch * 72 + rem];
        }
        __syncthreads();
        #pragma unroll
        for (int k = 0; k < 4; k++) {
            int o = tid + k * TPB_CONV;
            if (o < 32 * 49) {
                int c = o & 31, p = o >> 5;
                int py = p / 7, px = p % 7;
                int base = (2 * py) * 16 + 2 * px;
                for (int dic = 0; dic < 8; dic++) {
                    const float* xp = &xs2[(ch * 8 + dic) * 257 + base];
                    float P[16];
                    #pragma unroll
                    for (int r = 0; r < 4; r++)
                        #pragma unroll
                        for (int s = 0; s < 4; s++) P[r * 4 + s] = xp[r * 16 + s];
                    const float* wp = &wck[dic * 9 * 33 + c];
                    #pragma unroll
                    for (int ky = 0; ky < 3; ky++)
                        #pragma unroll
                        for (int kx = 0; kx < 3; kx++) {
                            float w = wp[(ky * 3 + kx) * 33];
                            acc[k][0] = fmaf(P[ky * 4 + kx],           w, acc[k][0]);
                            acc[k][1] = fmaf(P[ky * 4 + kx + 1],       w, acc[k][1]);
                            acc[k][2] = fmaf(P[(ky + 1) * 4 + kx],     w, acc[k][2]);
                            acc[k][3] = fmaf(P[(ky + 1) * 4 + kx + 1], w, acc[k][3]);
                        }
                }
            }
        }
    }
    #pragma unroll
    for (int k = 0; k < 4; k++) {
        int o = tid + k * TPB_CONV;
        if (o < 32 * 49) {
            int c = o & 31, p = o >> 5;
            int py = p / 7, px = p % 7;
            float v = fmaxf(fmaxf(fmaxf(acc[k][0], acc[k][1]),
                                  fmaxf(acc[k][2], acc[k][3])) + b2s[c], 0.f);
            xs3[c * 81 + (py + 1) * 9 + (px + 1)] = v;   // stride 81, gcd(81,32)=1
        }
    }

    // --- conv3 (32->32, 7x7) + relu + pool(floor: 7->3) -> out3 ---
    float a3[4] = {0.f, 0.f, 0.f, 0.f};
    int c3 = tid & 31, p3 = tid >> 5;
    int base3 = 0;
    if (tid < 288) {
        int py3 = p3 / 3, px3 = p3 % 3;
        base3 = (2 * py3) * 9 + 2 * px3;
    }
    for (int ch = 0; ch < 4; ch++) {
        __syncthreads();                           // orders conv2 wck reads / xs3 writes
        for (int i = tid; i < 2304; i += TPB_CONV) {
            int oc = i / 72, rem = i % 72;
            wck[rem * 33 + oc] = cw3[oc * 288 + ch * 72 + rem];
        }
        __syncthreads();
        if (tid < 288) {
            for (int dic = 0; dic < 8; dic++) {
                const float* xp = &xs3[(ch * 8 + dic) * 81 + base3];
                float P[16];
                #pragma unroll
                for (int r = 0; r < 4; r++)
                    #pragma unroll
                    for (int s = 0; s < 4; s++) P[r * 4 + s] = xp[r * 9 + s];
                const float* wp = &wck[dic * 9 * 33 + c3];
                #pragma unroll
                for (int ky = 0; ky < 3; ky++)
                    #pragma unroll
                    for (int kx = 0; kx < 3; kx++) {
                        float w = wp[(ky * 3 + kx) * 33];
                        a3[0] = fmaf(P[ky * 4 + kx],           w, a3[0]);
                        a3[1] = fmaf(P[ky * 4 + kx + 1],       w, a3[1]);
                        a3[2] = fmaf(P[(ky + 1) * 4 + kx],     w, a3[2]);
                        a3[3] = fmaf(P[(ky + 1) * 4 + kx + 1], w, a3[3]);
                    }
            }
        }
    }
    if (tid < 288) {
        float v = fmaxf(fmaxf(fmaxf(a3[0], a3[1]), fmaxf(a3[2], a3[3])) + b3s[c3], 0.f);
        out3[img * 288 + tid] = v;                 // coalesced; tid = p*32 + c
    }
}

// ---------------------------------------------------------------------------
// Kernel 2: BatchNorm train-mode stats -> per-channel scale/shift (a, b)
//   a = g * rsqrt(var + eps); b = beta - a * mean
// ---------------------------------------------------------------------------
__global__ __launch_bounds__(256) void bn_stats_kernel(
    const float* __restrict__ out3,
    const float* __restrict__ bng, const float* __restrict__ bnb,
    float* __restrict__ stats)
{
    const int c = blockIdx.x;
    const int tid = threadIdx.x;
    float s = 0.f, ss = 0.f;
    for (int j = tid; j < 4096 * 9; j += 256) {
        int imgp = j / 9, p = j - imgp * 9;
        float v = out3[imgp * 288 + p * 32 + c];
        s += v;
        ss = fmaf(v, v, ss);
    }
    __shared__ float rs[4], rss[4];
    int lane = tid & 63, wid = tid >> 6;
    #pragma unroll
    for (int off = 32; off > 0; off >>= 1) {
        s  += __shfl_down(s, off);
        ss += __shfl_down(ss, off);
    }
    if (lane == 0) { rs[wid] = s; rss[wid] = ss; }
    __syncthreads();
    if (tid == 0) {
        float S = rs[0] + rs[1] + rs[2] + rs[3];
        float SS = rss[0] + rss[1] + rss[2] + rss[3];
        const float inv_n = 1.f / (4096.f * 9.f);
        float mean = S * inv_n;
        float var = SS * inv_n - mean * mean;
        float a = bng[c] * rsqrtf(var + 1e-5f);
        stats[c] = a;
        stats[32 + c] = bnb[c] - a * mean;
    }
}

// ---------------------------------------------------------------------------
// Kernel 3: BN-apply + MLP (288->128->128->3) + argmax + 3 selection layers.
// 8 examples per block of 128 threads; thread = output neuron; weights read
// once per j-iteration, FMA'd into 8 accumulators.
// ---------------------------------------------------------------------------
__global__ __launch_bounds__(128) void mlp_select_kernel(
    const float* __restrict__ out3, const float* __restrict__ stats,
    const float* __restrict__ pw1, const float* __restrict__ pb1,
    const float* __restrict__ pw2, const float* __restrict__ pb2,
    const float* __restrict__ pw3, const float* __restrict__ pb3,
    const float* __restrict__ ew1, const float* __restrict__ eb1,
    const float* __restrict__ ew2, const float* __restrict__ eb2,
    const float* __restrict__ ew3, const float* __restrict__ eb3,
    float* __restrict__ out)
{
    const int tid = threadIdx.x;
    const int img0 = blockIdx.x * 8;

    __shared__ float ys[8 * 288];    // BN-normalized conv features, [e][p*32+c] order
    __shared__ float hA[8 * 128];
    __shared__ float hB[8 * 128];
    __shared__ float lg[24];
    __shared__ int   acts[8];
    __shared__ float sa[32], sb[32];

    if (tid < 32) { sa[tid] = stats[tid]; sb[tid] = stats[32 + tid]; }
    __syncthreads();

    // stage + BN-normalize 8 examples (fully coalesced; 288 % 32 == 0 so c = idx&31)
    for (int idx = tid; idx < 8 * 288; idx += 128) {
        int c = idx & 31;
        ys[idx] = fmaf(sa[c], out3[img0 * 288 + idx], sb[c]);
    }
    __syncthreads();

    float acc[8];

    // layer 1: 288 -> 128, relu.  storage index j = p*32+c  <->  weight row i = c*9+p
    #pragma unroll
    for (int e = 0; e < 8; e++) acc[e] = pb1[tid];
    for (int j = 0; j < 288; j++) {
        int i = (j & 31) * 9 + (j >> 5);
        float w = pw1[i * 128 + tid];
        #pragma unroll
        for (int e = 0; e < 8; e++) acc[e] = fmaf(ys[e * 288 + j], w, acc[e]);
    }
    #pragma unroll
    for (int e = 0; e < 8; e++) hA[e * 128 + tid] = fmaxf(acc[e], 0.f);
    __syncthreads();

    // layer 2: 128 -> 128, relu
    #pragma unroll
    for (int e = 0; e < 8; e++) acc[e] = pb2[tid];
    for (int j = 0; j < 128; j++) {
        float w = pw2[j * 128 + tid];
        #pragma unroll
        for (int e = 0; e < 8; e++) acc[e] = fmaf(hA[e * 128 + j], w, acc[e]);
    }
    #pragma unroll
    for (int e = 0; e < 8; e++) hB[e * 128 + tid] = fmaxf(acc[e], 0.f);
    __syncthreads();

    // logits 128 -> 3, argmax (first-max-wins, matches jnp.argmax)
    if (tid < 24) {
        int e = tid / 3, o = tid - e * 3;
        float sacc = pb3[o];
        for (int i = 0; i < 128; i++) sacc = fmaf(hB[e * 128 + i], pw3[i * 3 + o], sacc);
        lg[tid] = sacc;
    }
    __syncthreads();
    if (tid < 8) {
        float l0 = lg[tid * 3], l1 = lg[tid * 3 + 1], l2 = lg[tid * 3 + 2];
        int a = 0; float best = l0;
        if (l1 > best) { best = l1; a = 1; }
        if (l2 > best) { best = l2; a = 2; }
        acts[tid] = a;
        out[4096 * 10 + img0 + tid] = (float)a;   // actions output (as float)
    }
    __syncthreads();

    int ae[8];
    #pragma unroll
    for (int e = 0; e < 8; e++) ae[e] = acts[e];

    // selection layer 1: 288 -> 128 (no relu), per-example expert
    #pragma unroll
    for (int e = 0; e < 8; e++) acc[e] = 0.f;
    for (int j = 0; j < 288; j++) {
        int i = (j & 31) * 9 + (j >> 5);
        float w0 = ew1[i * 128 + tid];
        float w1 = ew1[36864 + i * 128 + tid];
        float w2 = ew1[73728 + i * 128 + tid];
        #pragma unroll
        for (int e = 0; e < 8; e++) {
            float w = (ae[e] == 0) ? w0 : ((ae[e] == 1) ? w1 : w2);
            acc[e] = fmaf(ys[e * 288 + j], w, acc[e]);
        }
    }
    __syncthreads();   // hA still being read? no: layer2 done; safe to overwrite after sync
    #pragma unroll
    for (int e = 0; e < 8; e++) hA[e * 128 + tid] = acc[e] + eb1[ae[e] * 128 + tid];
    __syncthreads();

    // selection layer 2: 128 -> 128 (no relu)
    #pragma unroll
    for (int e = 0; e < 8; e++) acc[e] = 0.f;
    for (int j = 0; j < 128; j++) {
        float w0 = ew2[j * 128 + tid];
        float w1 = ew2[16384 + j * 128 + tid];
        float w2 = ew2[32768 + j * 128 + tid];
        #pragma unroll
        for (int e = 0; e < 8; e++) {
            float w = (ae[e] == 0) ? w0 : ((ae[e] == 1) ? w1 : w2);
            acc[e] = fmaf(hA[e * 128 + j], w, acc[e]);
        }
    }
    #pragma unroll
    for (int e = 0; e < 8; e++) hB[e * 128 + tid] = acc[e] + eb2[ae[e] * 128 + tid];
    __syncthreads();

    // selection layer 3: 128 -> 10 (no relu), write final output
    if (tid < 80) {
        int e = tid / 10, o = tid - e * 10;
        int a = acts[e];
        float sacc = eb3[a * 10 + o];
        const float* w3 = &ew3[a * 1280];
        for (int i = 0; i < 128; i++) sacc = fmaf(hB[e * 128 + i], w3[i * 10 + o], sacc);
        out[(img0 + e) * 10 + o] = sacc;
    }
}

// ---------------------------------------------------------------------------
extern "C" void kernel_launch(void* const* d_in, const int* in_sizes, int n_in,
                              void* d_out, int out_size, void* d_ws, size_t ws_size,
                              hipStream_t stream)
{
    const float* x   = (const float*)d_in[0];
    const float* cw1 = (const float*)d_in[1];
    const float* cb1 = (const float*)d_in[2];
    const float* cw2 = (const float*)d_in[3];
    const float* cb2 = (const float*)d_in[4];
    const float* cw3 = (const float*)d_in[5];
    const float* cb3 = (const float*)d_in[6];
    const float* bng = (const float*)d_in[7];
    const float* bnb = (const float*)d_in[8];
    const float* pw1 = (const float*)d_in[9];
    const float* pb1 = (const float*)d_in[10];
    const float* pw2 = (const float*)d_in[11];
    const float* pb2 = (const float*)d_in[12];
    const float* pw3 = (const float*)d_in[13];
    const float* pb3 = (const float*)d_in[14];
    const float* ew1 = (const float*)d_in[15];
    const float* eb1 = (const float*)d_in[16];
    const float* ew2 = (const float*)d_in[17];
    const float* eb2 = (const float*)d_in[18];
    const float* ew3 = (const float*)d_in[19];
    const float* eb3 = (const float*)d_in[20];

    float* out   = (float*)d_out;
    float* out3  = (float*)d_ws;                 // 4096*288 floats = 4.72 MB
    float* stats = out3 + 4096 * 288;            // 64 floats

    fused_conv_kernel<<<4096, TPB_CONV, 0, stream>>>(x, cw1, cb1, cw2, cb2, cw3, cb3, out3);
    bn_stats_kernel<<<32, 256, 0, stream>>>(out3, bng, bnb, stats);
    mlp_select_kernel<<<512, 128, 0, stream>>>(out3, stats,
                                               pw1, pb1, pw2, pb2, pw3, pb3,
                                               ew1, eb1, ew2, eb2, ew3, eb3, out);
}

// Round 2
// 625.010 us; speedup vs baseline: 6.3370x; 6.3370x over previous
//
#include <hip/hip_runtime.h>

#define TPB_CONV 512

// ---------------------------------------------------------------------------
// Kernel 1: fused conv1+pool -> conv2+pool -> conv3+pool, one image per block.
// All intermediates live in LDS. Output: out3[img][p(9)][c(32)]  (p*32+c order)
//
// conv2 thread mapping: thread owns 4 channels (c=4*cb+k) at ONE pooled
// position -> P[16] patch shared across the 4 outputs, weights read as float4.
// This keeps peak live VGPRs ~50 (round-1 version spilled 13.9 GB to scratch).
// ---------------------------------------------------------------------------
__global__ __launch_bounds__(TPB_CONV, 4) void fused_conv_kernel(
    const float* __restrict__ x,
    const float* __restrict__ cw1, const float* __restrict__ cb1,
    const float* __restrict__ cw2, const float* __restrict__ cb2,
    const float* __restrict__ cw3, const float* __restrict__ cb3,
    float* __restrict__ out3)
{
    const int img = blockIdx.x;
    const int tid = threadIdx.x;

    __shared__ float xs1[900];        // 30x30 zero-padded input image
    __shared__ float w1s[288];        // conv1 weights [tap][oc]
    __shared__ float b1s[32], b2s[32], b3s[32];
    __shared__ float xs2[32 * 258];   // conv1 out / conv2 in: [ic][16x16 pad], stride 258 (even -> float2 ok)
    __shared__ float wck[72 * 36];    // conv2/3 weight chunk: [dic*9+tap][oc], stride 36 (float4-aligned)
    __shared__ float xs3[32 * 81];    // conv2 out / conv3 in: [ic][9x9 pad]

    // --- zero LDS (borders stay zero = implicit padding) ---
    for (int i = tid; i < 900;      i += TPB_CONV) xs1[i] = 0.f;
    for (int i = tid; i < 32 * 258; i += TPB_CONV) xs2[i] = 0.f;
    for (int i = tid; i < 32 * 81;  i += TPB_CONV) xs3[i] = 0.f;
    __syncthreads();

    // --- stage input image + conv1 weights ---
    for (int i = tid; i < 784; i += TPB_CONV) {
        int yy = i / 28, xx = i % 28;
        xs1[(yy + 1) * 30 + xx + 1] = x[img * 784 + i];
    }
    for (int i = tid; i < 288; i += TPB_CONV) {
        int oc = i & 31, tap = i >> 5;            // i = tap*32 + oc
        w1s[i] = cw1[oc * 9 + tap];
    }
    if (tid < 32) { b1s[tid] = cb1[tid]; b2s[tid] = cb2[tid]; b3s[tid] = cb3[tid]; }
    __syncthreads();

    // --- conv1 (1->32, 28x28) + relu + pool -> xs2 interior (14x14) ---
    for (int o = tid; o < 32 * 196; o += TPB_CONV) {
        int c = o & 31, p = o >> 5;               // 32 lanes share p -> broadcast patch reads
        int py = p / 14, px = p % 14;
        int base = (2 * py) * 30 + 2 * px;
        float P[16];
        #pragma unroll
        for (int r = 0; r < 4; r++)
            #pragma unroll
            for (int s = 0; s < 4; s++)
                P[r * 4 + s] = xs1[base + r * 30 + s];
        float a00 = 0.f, a01 = 0.f, a10 = 0.f, a11 = 0.f;
        #pragma unroll
        for (int ky = 0; ky < 3; ky++)
            #pragma unroll
            for (int kx = 0; kx < 3; kx++) {
                float w = w1s[(ky * 3 + kx) * 32 + c];
                a00 = fmaf(P[ky * 4 + kx],           w, a00);
                a01 = fmaf(P[ky * 4 + kx + 1],       w, a01);
                a10 = fmaf(P[(ky + 1) * 4 + kx],     w, a10);
                a11 = fmaf(P[(ky + 1) * 4 + kx + 1], w, a11);
            }
        // relu(max+b) == max(relu(ai+b)) since same bias, relu monotone
        float v = fmaxf(fmaxf(fmaxf(a00, a01), fmaxf(a10, a11)) + b1s[c], 0.f);
        xs2[c * 258 + (py + 1) * 16 + (px + 1)] = v;
    }

    // --- conv2 (32->32, 14x14) + relu + pool -> xs3 interior (7x7) ---
    // thread (tid<392): cb=tid&7, p=tid>>3; computes channels c=4*cb+k, k=0..3
    float acc[4][4];
    #pragma unroll
    for (int k = 0; k < 4; k++)
        #pragma unroll
        for (int q = 0; q < 4; q++) acc[k][q] = 0.f;

    const int cb2i = tid & 7;
    const int p2i  = tid >> 3;
    const int py2  = p2i / 7, px2 = p2i % 7;
    const int base2 = (2 * py2) * 16 + 2 * px2;   // even -> float2-aligned

    for (int ch = 0; ch < 4; ch++) {              // 4 chunks of 8 input channels
        __syncthreads();
        for (int i = tid; i < 2304; i += TPB_CONV) {
            int oc = i / 72, rem = i % 72;        // rem = dic*9 + tap
            wck[rem * 36 + oc] = cw2[oc * 288 + ch * 72 + rem];
        }
        __syncthreads();
        if (tid < 392) {
            for (int dic = 0; dic < 8; dic++) {
                const float* xp = &xs2[(ch * 8 + dic) * 258 + base2];
                float P[16];
                #pragma unroll
                for (int r = 0; r < 4; r++) {
                    float2 u0 = *(const float2*)(xp + r * 16);
                    float2 u1 = *(const float2*)(xp + r * 16 + 2);
                    P[r * 4 + 0] = u0.x; P[r * 4 + 1] = u0.y;
                    P[r * 4 + 2] = u1.x; P[r * 4 + 3] = u1.y;
                }
                const float* wrow = &wck[dic * 9 * 36 + cb2i * 4];
                #pragma unroll
                for (int tap = 0; tap < 9; tap++) {
                    const int ky = tap / 3, kx = tap % 3;
                    float4 wv = *(const float4*)(wrow + tap * 36);
                    float x00 = P[ky * 4 + kx];
                    float x01 = P[ky * 4 + kx + 1];
                    float x10 = P[(ky + 1) * 4 + kx];
                    float x11 = P[(ky + 1) * 4 + kx + 1];
                    float wk[4] = {wv.x, wv.y, wv.z, wv.w};
                    #pragma unroll
                    for (int k = 0; k < 4; k++) {
                        acc[k][0] = fmaf(x00, wk[k], acc[k][0]);
                        acc[k][1] = fmaf(x01, wk[k], acc[k][1]);
                        acc[k][2] = fmaf(x10, wk[k], acc[k][2]);
                        acc[k][3] = fmaf(x11, wk[k], acc[k][3]);
                    }
                }
            }
        }
    }
    if (tid < 392) {
        #pragma unroll
        for (int k = 0; k < 4; k++) {
            int c = cb2i * 4 + k;
            float v = fmaxf(fmaxf(fmaxf(acc[k][0], acc[k][1]),
                                  fmaxf(acc[k][2], acc[k][3])) + b2s[c], 0.f);
            xs3[c * 81 + (py2 + 1) * 9 + (px2 + 1)] = v;   // stride 81, gcd(81,32)=1
        }
    }

    // --- conv3 (32->32, 7x7) + relu + pool(floor: 7->3) -> out3 ---
    float a3[4] = {0.f, 0.f, 0.f, 0.f};
    int c3 = tid & 31, p3 = tid >> 5;
    int base3 = 0;
    if (tid < 288) {
        int py3 = p3 / 3, px3 = p3 % 3;
        base3 = (2 * py3) * 9 + 2 * px3;
    }
    for (int ch = 0; ch < 4; ch++) {
        __syncthreads();                           // orders conv2 wck reads / xs3 writes
        for (int i = tid; i < 2304; i += TPB_CONV) {
            int oc = i / 72, rem = i % 72;
            wck[rem * 36 + oc] = cw3[oc * 288 + ch * 72 + rem];
        }
        __syncthreads();
        if (tid < 288) {
            for (int dic = 0; dic < 8; dic++) {
                const float* xp = &xs3[(ch * 8 + dic) * 81 + base3];
                float P[16];
                #pragma unroll
                for (int r = 0; r < 4; r++)
                    #pragma unroll
                    for (int s = 0; s < 4; s++) P[r * 4 + s] = xp[r * 9 + s];
                const float* wp = &wck[dic * 9 * 36 + c3];
                #pragma unroll
                for (int ky = 0; ky < 3; ky++)
                    #pragma unroll
                    for (int kx = 0; kx < 3; kx++) {
                        float w = wp[(ky * 3 + kx) * 36];
                        a3[0] = fmaf(P[ky * 4 + kx],           w, a3[0]);
                        a3[1] = fmaf(P[ky * 4 + kx + 1],       w, a3[1]);
                        a3[2] = fmaf(P[(ky + 1) * 4 + kx],     w, a3[2]);
                        a3[3] = fmaf(P[(ky + 1) * 4 + kx + 1], w, a3[3]);
                    }
            }
        }
    }
    if (tid < 288) {
        float v = fmaxf(fmaxf(fmaxf(a3[0], a3[1]), fmaxf(a3[2], a3[3])) + b3s[c3], 0.f);
        out3[img * 288 + tid] = v;                 // coalesced; tid = p*32 + c
    }
}

// ---------------------------------------------------------------------------
// Kernel 2: BatchNorm train-mode stats -> per-channel scale/shift (a, b)
//   a = g * rsqrt(var + eps); b = beta - a * mean
// ---------------------------------------------------------------------------
__global__ __launch_bounds__(256) void bn_stats_kernel(
    const float* __restrict__ out3,
    const float* __restrict__ bng, const float* __restrict__ bnb,
    float* __restrict__ stats)
{
    const int c = blockIdx.x;
    const int tid = threadIdx.x;
    float s = 0.f, ss = 0.f;
    for (int j = tid; j < 4096 * 9; j += 256) {
        int imgp = j / 9, p = j - imgp * 9;
        float v = out3[imgp * 288 + p * 32 + c];
        s += v;
        ss = fmaf(v, v, ss);
    }
    __shared__ float rs[4], rss[4];
    int lane = tid & 63, wid = tid >> 6;
    #pragma unroll
    for (int off = 32; off > 0; off >>= 1) {
        s  += __shfl_down(s, off);
        ss += __shfl_down(ss, off);
    }
    if (lane == 0) { rs[wid] = s; rss[wid] = ss; }
    __syncthreads();
    if (tid == 0) {
        float S = rs[0] + rs[1] + rs[2] + rs[3];
        float SS = rss[0] + rss[1] + rss[2] + rss[3];
        const float inv_n = 1.f / (4096.f * 9.f);
        float mean = S * inv_n;
        float var = SS * inv_n - mean * mean;
        float a = bng[c] * rsqrtf(var + 1e-5f);
        stats[c] = a;
        stats[32 + c] = bnb[c] - a * mean;
    }
}

// ---------------------------------------------------------------------------
// Kernel 3: BN-apply + MLP (288->128->128->3) + argmax + 3 selection layers.
// 8 examples per block of 128 threads; thread = output neuron; weights read
// once per j-iteration, FMA'd into 8 accumulators.
// ---------------------------------------------------------------------------
__global__ __launch_bounds__(128) void mlp_select_kernel(
    const float* __restrict__ out3, const float* __restrict__ stats,
    const float* __restrict__ pw1, const float* __restrict__ pb1,
    const float* __restrict__ pw2, const float* __restrict__ pb2,
    const float* __restrict__ pw3, const float* __restrict__ pb3,
    const float* __restrict__ ew1, const float* __restrict__ eb1,
    const float* __restrict__ ew2, const float* __restrict__ eb2,
    const float* __restrict__ ew3, const float* __restrict__ eb3,
    float* __restrict__ out)
{
    const int tid = threadIdx.x;
    const int img0 = blockIdx.x * 8;

    __shared__ float ys[8 * 288];    // BN-normalized conv features, [e][p*32+c] order
    __shared__ float hA[8 * 128];
    __shared__ float hB[8 * 128];
    __shared__ float lg[24];
    __shared__ int   acts[8];
    __shared__ float sa[32], sb[32];

    if (tid < 32) { sa[tid] = stats[tid]; sb[tid] = stats[32 + tid]; }
    __syncthreads();

    // stage + BN-normalize 8 examples (fully coalesced; 288 % 32 == 0 so c = idx&31)
    for (int idx = tid; idx < 8 * 288; idx += 128) {
        int c = idx & 31;
        ys[idx] = fmaf(sa[c], out3[img0 * 288 + idx], sb[c]);
    }
    __syncthreads();

    float acc[8];

    // layer 1: 288 -> 128, relu.  storage index j = p*32+c  <->  weight row i = c*9+p
    #pragma unroll
    for (int e = 0; e < 8; e++) acc[e] = pb1[tid];
    for (int j = 0; j < 288; j++) {
        int i = (j & 31) * 9 + (j >> 5);
        float w = pw1[i * 128 + tid];
        #pragma unroll
        for (int e = 0; e < 8; e++) acc[e] = fmaf(ys[e * 288 + j], w, acc[e]);
    }
    #pragma unroll
    for (int e = 0; e < 8; e++) hA[e * 128 + tid] = fmaxf(acc[e], 0.f);
    __syncthreads();

    // layer 2: 128 -> 128, relu
    #pragma unroll
    for (int e = 0; e < 8; e++) acc[e] = pb2[tid];
    for (int j = 0; j < 128; j++) {
        float w = pw2[j * 128 + tid];
        #pragma unroll
        for (int e = 0; e < 8; e++) acc[e] = fmaf(hA[e * 128 + j], w, acc[e]);
    }
    #pragma unroll
    for (int e = 0; e < 8; e++) hB[e * 128 + tid] = fmaxf(acc[e], 0.f);
    __syncthreads();

    // logits 128 -> 3, argmax (first-max-wins, matches jnp.argmax)
    if (tid < 24) {
        int e = tid / 3, o = tid - e * 3;
        float sacc = pb3[o];
        for (int i = 0; i < 128; i++) sacc = fmaf(hB[e * 128 + i], pw3[i * 3 + o], sacc);
        lg[tid] = sacc;
    }
    __syncthreads();
    if (tid < 8) {
        float l0 = lg[tid * 3], l1 = lg[tid * 3 + 1], l2 = lg[tid * 3 + 2];
        int a = 0; float best = l0;
        if (l1 > best) { best = l1; a = 1; }
        if (l2 > best) { best = l2; a = 2; }
        acts[tid] = a;
        out[4096 * 10 + img0 + tid] = (float)a;   // actions output (as float)
    }
    __syncthreads();

    int ae[8];
    #pragma unroll
    for (int e = 0; e < 8; e++) ae[e] = acts[e];

    // selection layer 1: 288 -> 128 (no relu), per-example expert
    #pragma unroll
    for (int e = 0; e < 8; e++) acc[e] = 0.f;
    for (int j = 0; j < 288; j++) {
        int i = (j & 31) * 9 + (j >> 5);
        float w0 = ew1[i * 128 + tid];
        float w1 = ew1[36864 + i * 128 + tid];
        float w2 = ew1[73728 + i * 128 + tid];
        #pragma unroll
        for (int e = 0; e < 8; e++) {
            float w = (ae[e] == 0) ? w0 : ((ae[e] == 1) ? w1 : w2);
            acc[e] = fmaf(ys[e * 288 + j], w, acc[e]);
        }
    }
    __syncthreads();
    #pragma unroll
    for (int e = 0; e < 8; e++) hA[e * 128 + tid] = acc[e] + eb1[ae[e] * 128 + tid];
    __syncthreads();

    // selection layer 2: 128 -> 128 (no relu)
    #pragma unroll
    for (int e = 0; e < 8; e++) acc[e] = 0.f;
    for (int j = 0; j < 128; j++) {
        float w0 = ew2[j * 128 + tid];
        float w1 = ew2[16384 + j * 128 + tid];
        float w2 = ew2[32768 + j * 128 + tid];
        #pragma unroll
        for (int e = 0; e < 8; e++) {
            float w = (ae[e] == 0) ? w0 : ((ae[e] == 1) ? w1 : w2);
            acc[e] = fmaf(hA[e * 128 + j], w, acc[e]);
        }
    }
    #pragma unroll
    for (int e = 0; e < 8; e++) hB[e * 128 + tid] = acc[e] + eb2[ae[e] * 128 + tid];
    __syncthreads();

    // selection layer 3: 128 -> 10 (no relu), write final output
    if (tid < 80) {
        int e = tid / 10, o = tid - e * 10;
        int a = acts[e];
        float sacc = eb3[a * 10 + o];
        const float* w3 = &ew3[a * 1280];
        for (int i = 0; i < 128; i++) sacc = fmaf(hB[e * 128 + i], w3[i * 10 + o], sacc);
        out[(img0 + e) * 10 + o] = sacc;
    }
}

// ---------------------------------------------------------------------------
extern "C" void kernel_launch(void* const* d_in, const int* in_sizes, int n_in,
                              void* d_out, int out_size, void* d_ws, size_t ws_size,
                              hipStream_t stream)
{
    const float* x   = (const float*)d_in[0];
    const float* cw1 = (const float*)d_in[1];
    const float* cb1 = (const float*)d_in[2];
    const float* cw2 = (const float*)d_in[3];
    const float* cb2 = (const float*)d_in[4];
    const float* cw3 = (const float*)d_in[5];
    const float* cb3 = (const float*)d_in[6];
    const float* bng = (const float*)d_in[7];
    const float* bnb = (const float*)d_in[8];
    const float* pw1 = (const float*)d_in[9];
    const float* pb1 = (const float*)d_in[10];
    const float* pw2 = (const float*)d_in[11];
    const float* pb2 = (const float*)d_in[12];
    const float* pw3 = (const float*)d_in[13];
    const float* pb3 = (const float*)d_in[14];
    const float* ew1 = (const float*)d_in[15];
    const float* eb1 = (const float*)d_in[16];
    const float* ew2 = (const float*)d_in[17];
    const float* eb2 = (const float*)d_in[18];
    const float* ew3 = (const float*)d_in[19];
    const float* eb3 = (const float*)d_in[20];

    float* out   = (float*)d_out;
    float* out3  = (float*)d_ws;                 // 4096*288 floats = 4.72 MB
    float* stats = out3 + 4096 * 288;            // 64 floats

    fused_conv_kernel<<<4096, TPB_CONV, 0, stream>>>(x, cw1, cb1, cw2, cb2, cw3, cb3, out3);
    bn_stats_kernel<<<32, 256, 0, stream>>>(out3, bng, bnb, stats);
    mlp_select_kernel<<<512, 128, 0, stream>>>(out3, stats,
                                               pw1, pb1, pw2, pb2, pw3, pb3,
                                               ew1, eb1, ew2, eb2, ew3, eb3, out);
}

// Round 3
// 591.593 us; speedup vs baseline: 6.6950x; 1.0565x over previous
//
#include <hip/hip_runtime.h>

// ---------------------------------------------------------------------------
// Kernel 0: repack conv2/conv3 weights from [oc][ic][tap] into chunk-linear
// [ch][rem=ld*9+tap][oc] so the fused kernel can stage coalesced+linear.
// ---------------------------------------------------------------------------
__global__ __launch_bounds__(256) void repack_kernel(
    const float* __restrict__ cw2, const float* __restrict__ cw3,
    float* __restrict__ packed2, float* __restrict__ packed3)
{
    int t = blockIdx.x * 256 + threadIdx.x;   // grid 72*256 = 18432 = 2*9216
    if (t < 9216) {
        int oc = t & 31, r = t >> 5;          // r = ch*72 + rem in [0,288)
        packed2[t] = cw2[oc * 288 + r];
    } else {
        int t2 = t - 9216;
        int oc = t2 & 31, r = t2 >> 5;
        packed3[t2] = cw3[oc * 288 + r];
    }
}

// ---------------------------------------------------------------------------
// Kernel 1: fused conv1+pool -> conv2+pool -> conv3+pool, one image per block.
// conv2: thread = 4oc x 14-col prepool row, K-split-4 over lockstep 8-dic
// chunks; xs2 = 16x16 planes with XOR-swizzled col-quads (b128 reads, <=2-way
// conflicts). K-partials reduced via LDS; pooling through prepool buffer.
// ---------------------------------------------------------------------------
__global__ __launch_bounds__(512, 4) void fused_conv_kernel(
    const float* __restrict__ x,
    const float* __restrict__ cw1, const float* __restrict__ cb1,
    const float* __restrict__ packed2, const float* __restrict__ cb2,
    const float* __restrict__ packed3, const float* __restrict__ cb3,
    float* __restrict__ out3)
{
    const int img = blockIdx.x;
    const int tid = threadIdx.x;

    __shared__ float xs1[900];        // 30x30 zero-padded input image
    __shared__ float w1s[288];        // conv1 weights [tap][oc]
    __shared__ float b1s[32], b2s[32], b3s[32];
    __shared__ float pool2[8192];     // 32KB: xs2 (32 x 16x16 swizzled planes) / red / prepool
    __shared__ float wck[2304];       // 9KB: 8-dic weight chunk [ld*9+tap][oc32]
    __shared__ float xs3[32 * 81];    // conv3 input: [ic][9x9 padded]

    // --- zero LDS (borders stay zero = implicit padding) ---
    for (int i = tid; i < 900;  i += 512) xs1[i] = 0.f;
    for (int i = tid; i < 8192; i += 512) pool2[i] = 0.f;
    for (int i = tid; i < 2592; i += 512) xs3[i] = 0.f;
    __syncthreads();

    // --- stage input image + conv1 weights ---
    for (int i = tid; i < 784; i += 512) {
        int yy = i / 28, xx = i % 28;
        xs1[(yy + 1) * 30 + xx + 1] = x[img * 784 + i];
    }
    for (int i = tid; i < 288; i += 512) {
        int oc = i & 31, tap = i >> 5;
        w1s[i] = cw1[oc * 9 + tap];
    }
    if (tid < 32) { b1s[tid] = cb1[tid]; b2s[tid] = cb2[tid]; b3s[tid] = cb3[tid]; }
    __syncthreads();

    // --- conv1 (1->32) + relu + pool -> swizzled xs2 planes in pool2 ---
    for (int o = tid; o < 32 * 196; o += 512) {
        int c = o & 31, p = o >> 5;               // 32 lanes share p -> broadcast reads
        int py = p / 14, px = p % 14;
        int base = (2 * py) * 30 + 2 * px;
        float P[16];
        #pragma unroll
        for (int r = 0; r < 4; r++)
            #pragma unroll
            for (int s = 0; s < 4; s++)
                P[r * 4 + s] = xs1[base + r * 30 + s];
        float a00 = 0.f, a01 = 0.f, a10 = 0.f, a11 = 0.f;
        #pragma unroll
        for (int ky = 0; ky < 3; ky++)
            #pragma unroll
            for (int kx = 0; kx < 3; kx++) {
                float w = w1s[(ky * 3 + kx) * 32 + c];
                a00 = fmaf(P[ky * 4 + kx],           w, a00);
                a01 = fmaf(P[ky * 4 + kx + 1],       w, a01);
                a10 = fmaf(P[(ky + 1) * 4 + kx],     w, a10);
                a11 = fmaf(P[(ky + 1) * 4 + kx + 1], w, a11);
            }
        float v = fmaxf(fmaxf(fmaxf(a00, a01), fmaxf(a10, a11)) + b1s[c], 0.f);
        int r = py + 1, cc = px + 1;              // padded coords
        pool2[c * 256 + r * 16 + ((((cc >> 2) + r) & 3) << 2) + (cc & 3)] = v;
    }

    // --- conv2: 4oc x 14-col row, K-split-4 over 4 lockstep chunks of 8 dic ---
    const int g  = tid >> 7;            // K-group 0..3 (whole waves)
    const int u  = tid & 127;           // unit; active if u < 112
    const int cb = u & 7, R = u >> 3;   // oc-quad, prepool row
    const int oc0 = cb * 4;
    const bool act2 = (u < 112);

    float acc[4][14];
    #pragma unroll
    for (int a = 0; a < 4; a++)
        #pragma unroll
        for (int c = 0; c < 14; c++) acc[a][c] = 0.f;

    float pf[5];
    #pragma unroll
    for (int k = 0; k < 5; k++) {
        int idx = tid + k * 512;
        pf[k] = (idx < 2304) ? packed2[idx] : 0.f;
    }

    for (int ch = 0; ch < 4; ch++) {
        __syncthreads();                          // conv1 writes / prior wck reads done
        #pragma unroll
        for (int k = 0; k < 5; k++) {
            int idx = tid + k * 512;
            if (idx < 2304) wck[idx] = pf[k];
        }
        if (ch < 3) {
            #pragma unroll
            for (int k = 0; k < 5; k++) {
                int idx = tid + k * 512;
                pf[k] = (idx < 2304) ? packed2[(ch + 1) * 2304 + idx] : 0.f;
            }
        }
        __syncthreads();
        if (act2) {
            #pragma unroll
            for (int d = 0; d < 2; d++) {
                const int ld = 2 * g + d;                 // local dic in chunk
                const int ic = ch * 8 + ld;
                const float* wd = &wck[ld * 288 + oc0];   // ld*9*32
                const int pb = ic * 256;
                #pragma unroll
                for (int ky = 0; ky < 3; ky++) {
                    const int r = R + ky;
                    const int rb = pb + r * 16;
                    float row[16];
                    #pragma unroll
                    for (int q = 0; q < 4; q++) {
                        const float4 t = *(const float4*)&pool2[rb + (((q + r) & 3) << 2)];
                        row[q * 4 + 0] = t.x; row[q * 4 + 1] = t.y;
                        row[q * 4 + 2] = t.z; row[q * 4 + 3] = t.w;
                    }
                    const float4 wa = *(const float4*)&wd[(ky * 3 + 0) * 32];
                    const float4 wb = *(const float4*)&wd[(ky * 3 + 1) * 32];
                    const float4 wc = *(const float4*)&wd[(ky * 3 + 2) * 32];
                    #pragma unroll
                    for (int c = 0; c < 14; c++) {
                        acc[0][c] = fmaf(row[c],     wa.x, acc[0][c]);
                        acc[1][c] = fmaf(row[c],     wa.y, acc[1][c]);
                        acc[2][c] = fmaf(row[c],     wa.z, acc[2][c]);
                        acc[3][c] = fmaf(row[c],     wa.w, acc[3][c]);
                        acc[0][c] = fmaf(row[c + 1], wb.x, acc[0][c]);
                        acc[1][c] = fmaf(row[c + 1], wb.y, acc[1][c]);
                        acc[2][c] = fmaf(row[c + 1], wb.z, acc[2][c]);
                        acc[3][c] = fmaf(row[c + 1], wb.w, acc[3][c]);
                        acc[0][c] = fmaf(row[c + 2], wc.x, acc[0][c]);
                        acc[1][c] = fmaf(row[c + 2], wc.y, acc[1][c]);
                        acc[2][c] = fmaf(row[c + 2], wc.z, acc[2][c]);
                        acc[3][c] = fmaf(row[c + 2], wc.w, acc[3][c]);
                    }
                }
            }
        }
    }

    // --- K-reduction (3 rounds) in dead xs2 region; red stride 57 (odd) ---
    __syncthreads();
    for (int s = 1; s < 4; s++) {
        if (g == s && act2) {
            #pragma unroll
            for (int a = 0; a < 4; a++)
                #pragma unroll
                for (int c = 0; c < 14; c++) pool2[u * 57 + a * 14 + c] = acc[a][c];
        }
        __syncthreads();
        if (g == 0 && act2) {
            #pragma unroll
            for (int a = 0; a < 4; a++)
                #pragma unroll
                for (int c = 0; c < 14; c++) acc[a][c] += pool2[u * 57 + a * 14 + c];
        }
        __syncthreads();
    }
    // g0 writes raw prepool to pp[oc][14 rows][16] (bias+relu applied at pool)
    if (g == 0 && act2) {
        #pragma unroll
        for (int a = 0; a < 4; a++)
            #pragma unroll
            for (int c = 0; c < 14; c++)
                pool2[(oc0 + a) * 224 + R * 16 + c] = acc[a][c];
    }
    __syncthreads();

    // --- pool 14x14 -> 7x7, bias+relu, into xs3 padded planes ---
    for (int j = tid; j < 1568; j += 512) {
        int ic = j & 31, p = j >> 5;
        int py = p / 7, px = p % 7;
        const float* q = &pool2[ic * 224 + (2 * py) * 16 + 2 * px];
        float v = fmaxf(fmaxf(q[0], q[1]), fmaxf(q[16], q[17]));
        v = fmaxf(v + b2s[ic], 0.f);
        xs3[ic * 81 + (py + 1) * 9 + (px + 1)] = v;
    }

    // --- conv3 (32->32, 7x7) + relu + pool(floor: 7->3) -> out3 ---
    float a3[4] = {0.f, 0.f, 0.f, 0.f};
    int c3 = tid & 31, p3 = tid >> 5;
    int base3 = 0;
    if (tid < 288) {
        int py3 = p3 / 3, px3 = p3 % 3;
        base3 = (2 * py3) * 9 + 2 * px3;
    }
    float pg[5];
    #pragma unroll
    for (int k = 0; k < 5; k++) {
        int idx = tid + k * 512;
        pg[k] = (idx < 2304) ? packed3[idx] : 0.f;
    }
    for (int ch = 0; ch < 4; ch++) {
        __syncthreads();
        #pragma unroll
        for (int k = 0; k < 5; k++) {
            int idx = tid + k * 512;
            if (idx < 2304) wck[idx] = pg[k];
        }
        if (ch < 3) {
            #pragma unroll
            for (int k = 0; k < 5; k++) {
                int idx = tid + k * 512;
                pg[k] = (idx < 2304) ? packed3[(ch + 1) * 2304 + idx] : 0.f;
            }
        }
        __syncthreads();
        if (tid < 288) {
            for (int dic = 0; dic < 8; dic++) {
                const float* xp = &xs3[(ch * 8 + dic) * 81 + base3];
                float P[16];
                #pragma unroll
                for (int r = 0; r < 4; r++)
                    #pragma unroll
                    for (int s = 0; s < 4; s++) P[r * 4 + s] = xp[r * 9 + s];
                const float* wp = &wck[dic * 288 + c3];
                #pragma unroll
                for (int ky = 0; ky < 3; ky++)
                    #pragma unroll
                    for (int kx = 0; kx < 3; kx++) {
                        float w = wp[(ky * 3 + kx) * 32];
                        a3[0] = fmaf(P[ky * 4 + kx],           w, a3[0]);
                        a3[1] = fmaf(P[ky * 4 + kx + 1],       w, a3[1]);
                        a3[2] = fmaf(P[(ky + 1) * 4 + kx],     w, a3[2]);
                        a3[3] = fmaf(P[(ky + 1) * 4 + kx + 1], w, a3[3]);
                    }
            }
        }
    }
    if (tid < 288) {
        float v = fmaxf(fmaxf(fmaxf(a3[0], a3[1]), fmaxf(a3[2], a3[3])) + b3s[c3], 0.f);
        out3[img * 288 + tid] = v;                 // tid = p*32 + c
    }
}

// ---------------------------------------------------------------------------
// Kernel 2a/2b: BatchNorm stats, two-stage
// ---------------------------------------------------------------------------
__global__ __launch_bounds__(256) void bn_part_kernel(
    const float* __restrict__ out3, float* __restrict__ pS, float* __restrict__ pSS)
{
    const int blk = blockIdx.x;                   // 64 blocks
    const int c = threadIdx.x & 31, ml = threadIdx.x >> 5;
    float s = 0.f, ss = 0.f;
    const int base = blk * 576 + ml;
    for (int k = 0; k < 72; k++) {
        float v = out3[(base + k * 8) * 32 + c];  // coalesced: 64 consecutive words/wave
        s += v; ss = fmaf(v, v, ss);
    }
    __shared__ float rs[256], rss[256];
    rs[threadIdx.x] = s; rss[threadIdx.x] = ss;
    __syncthreads();
    if (threadIdx.x < 32) {
        float S = 0.f, SS = 0.f;
        #pragma unroll
        for (int m = 0; m < 8; m++) { S += rs[threadIdx.x + 32 * m]; SS += rss[threadIdx.x + 32 * m]; }
        pS[blk * 32 + threadIdx.x] = S;
        pSS[blk * 32 + threadIdx.x] = SS;
    }
}

__global__ __launch_bounds__(64) void bn_final_kernel(
    const float* __restrict__ pS, const float* __restrict__ pSS,
    const float* __restrict__ bng, const float* __restrict__ bnb,
    float* __restrict__ stats)
{
    int c = threadIdx.x;
    if (c < 32) {
        float S = 0.f, SS = 0.f;
        for (int b = 0; b < 64; b++) { S += pS[b * 32 + c]; SS += pSS[b * 32 + c]; }
        const float inv_n = 1.f / (4096.f * 9.f);
        float mean = S * inv_n;
        float var = SS * inv_n - mean * mean;
        float a = bng[c] * rsqrtf(var + 1e-5f);
        stats[c] = a;
        stats[32 + c] = bnb[c] - a * mean;
    }
}

// ---------------------------------------------------------------------------
// Kernel 3: BN-apply + MLP + argmax + 3 selection layers.
// 256 threads, 16 examples; thread = (eT=tid>>6 -> 4 examples) x (n2=tid&63 ->
// 2 neurons). ys/h transposed in LDS (stride 20) -> broadcast b128 reads.
// ---------------------------------------------------------------------------
__global__ __launch_bounds__(256) void mlp_select_kernel(
    const float* __restrict__ out3, const float* __restrict__ stats,
    const float* __restrict__ pw1, const float* __restrict__ pb1,
    const float* __restrict__ pw2, const float* __restrict__ pb2,
    const float* __restrict__ pw3, const float* __restrict__ pb3,
    const float* __restrict__ ew1, const float* __restrict__ eb1,
    const float* __restrict__ ew2, const float* __restrict__ eb2,
    const float* __restrict__ ew3, const float* __restrict__ eb3,
    float* __restrict__ out)
{
    const int tid = threadIdx.x;
    const int img0 = blockIdx.x * 16;

    __shared__ float ysT[288 * 20];   // [j][e], stride 20
    __shared__ float hAT[128 * 20];
    __shared__ float hBT[128 * 20];
    __shared__ float lg[48];
    __shared__ int   acts[16];
    __shared__ float sa[32], sb[32];

    if (tid < 32) { sa[tid] = stats[tid]; sb[tid] = stats[32 + tid]; }
    __syncthreads();

    // stage + BN: 1152 float4 reads, scatter-transpose into ysT
    for (int it = 0; it < 5; it++) {
        int i4 = it * 256 + tid;
        if (i4 < 1152) {
            int e = i4 / 72, jq = i4 - e * 72;
            float4 v = *(const float4*)&out3[(img0 + e) * 288 + jq * 4];
            int j = jq * 4;
            ysT[(j + 0) * 20 + e] = fmaf(sa[(j + 0) & 31], v.x, sb[(j + 0) & 31]);
            ysT[(j + 1) * 20 + e] = fmaf(sa[(j + 1) & 31], v.y, sb[(j + 1) & 31]);
            ysT[(j + 2) * 20 + e] = fmaf(sa[(j + 2) & 31], v.z, sb[(j + 2) & 31]);
            ysT[(j + 3) * 20 + e] = fmaf(sa[(j + 3) & 31], v.w, sb[(j + 3) & 31]);
        }
    }
    __syncthreads();

    const int n2 = tid & 63, eT = tid >> 6, e0 = eT * 4;
    float acc[4][2];

    // layer 1: 288 -> 128, relu.  ys index j -> weight row i = (j&31)*9 + (j>>5)
    #pragma unroll
    for (int e = 0; e < 4; e++) { acc[e][0] = pb1[n2 * 2]; acc[e][1] = pb1[n2 * 2 + 1]; }
    for (int k = 0; k < 288; k++) {
        int i = (k & 31) * 9 + (k >> 5);
        float2 w = *(const float2*)&pw1[i * 128 + n2 * 2];
        float4 yv = *(const float4*)&ysT[k * 20 + e0];
        acc[0][0] = fmaf(yv.x, w.x, acc[0][0]); acc[0][1] = fmaf(yv.x, w.y, acc[0][1]);
        acc[1][0] = fmaf(yv.y, w.x, acc[1][0]); acc[1][1] = fmaf(yv.y, w.y, acc[1][1]);
        acc[2][0] = fmaf(yv.z, w.x, acc[2][0]); acc[2][1] = fmaf(yv.z, w.y, acc[2][1]);
        acc[3][0] = fmaf(yv.w, w.x, acc[3][0]); acc[3][1] = fmaf(yv.w, w.y, acc[3][1]);
    }
    #pragma unroll
    for (int e = 0; e < 4; e++)
        #pragma unroll
        for (int d = 0; d < 2; d++)
            hAT[(n2 * 2 + d) * 20 + e0 + e] = fmaxf(acc[e][d], 0.f);
    __syncthreads();

    // layer 2: 128 -> 128, relu
    #pragma unroll
    for (int e = 0; e < 4; e++) { acc[e][0] = pb2[n2 * 2]; acc[e][1] = pb2[n2 * 2 + 1]; }
    for (int k = 0; k < 128; k++) {
        float2 w = *(const float2*)&pw2[k * 128 + n2 * 2];
        float4 hv = *(const float4*)&hAT[k * 20 + e0];
        acc[0][0] = fmaf(hv.x, w.x, acc[0][0]); acc[0][1] = fmaf(hv.x, w.y, acc[0][1]);
        acc[1][0] = fmaf(hv.y, w.x, acc[1][0]); acc[1][1] = fmaf(hv.y, w.y, acc[1][1]);
        acc[2][0] = fmaf(hv.z, w.x, acc[2][0]); acc[2][1] = fmaf(hv.z, w.y, acc[2][1]);
        acc[3][0] = fmaf(hv.w, w.x, acc[3][0]); acc[3][1] = fmaf(hv.w, w.y, acc[3][1]);
    }
    #pragma unroll
    for (int e = 0; e < 4; e++)
        #pragma unroll
        for (int d = 0; d < 2; d++)
            hBT[(n2 * 2 + d) * 20 + e0 + e] = fmaxf(acc[e][d], 0.f);
    __syncthreads();

    // logits 128 -> 3
    if (tid < 48) {
        int e = tid / 3, o = tid - e * 3;
        float s = pb3[o];
        for (int k = 0; k < 128; k++) s = fmaf(hBT[k * 20 + e], pw3[k * 3 + o], s);
        lg[e * 3 + o] = s;
    }
    __syncthreads();
    if (tid < 16) {
        float l0 = lg[tid * 3], l1 = lg[tid * 3 + 1], l2 = lg[tid * 3 + 2];
        int a = 0; float best = l0;
        if (l1 > best) { best = l1; a = 1; }
        if (l2 > best) { best = l2; a = 2; }
        acts[tid] = a;
        out[4096 * 10 + img0 + tid] = (float)a;
    }
    __syncthreads();

    int ae[4];
    #pragma unroll
    for (int e = 0; e < 4; e++) ae[e] = acts[e0 + e];

    // selection layer 1: 288 -> 128
    #pragma unroll
    for (int e = 0; e < 4; e++) { acc[e][0] = 0.f; acc[e][1] = 0.f; }
    for (int k = 0; k < 288; k++) {
        int i = (k & 31) * 9 + (k >> 5);
        float2 w0 = *(const float2*)&ew1[i * 128 + n2 * 2];
        float2 w1 = *(const float2*)&ew1[36864 + i * 128 + n2 * 2];
        float2 w2 = *(const float2*)&ew1[73728 + i * 128 + n2 * 2];
        float4 yv = *(const float4*)&ysT[k * 20 + e0];
        float ye[4] = {yv.x, yv.y, yv.z, yv.w};
        #pragma unroll
        for (int e = 0; e < 4; e++) {
            float wx = (ae[e] == 0) ? w0.x : ((ae[e] == 1) ? w1.x : w2.x);
            float wy = (ae[e] == 0) ? w0.y : ((ae[e] == 1) ? w1.y : w2.y);
            acc[e][0] = fmaf(ye[e], wx, acc[e][0]);
            acc[e][1] = fmaf(ye[e], wy, acc[e][1]);
        }
    }
    #pragma unroll
    for (int e = 0; e < 4; e++)
        #pragma unroll
        for (int d = 0; d < 2; d++)
            hAT[(n2 * 2 + d) * 20 + e0 + e] = acc[e][d] + eb1[ae[e] * 128 + n2 * 2 + d];
    __syncthreads();

    // selection layer 2: 128 -> 128
    #pragma unroll
    for (int e = 0; e < 4; e++) { acc[e][0] = 0.f; acc[e][1] = 0.f; }
    for (int k = 0; k < 128; k++) {
        float2 w0 = *(const float2*)&ew2[k * 128 + n2 * 2];
        float2 w1 = *(const float2*)&ew2[16384 + k * 128 + n2 * 2];
        float2 w2 = *(const float2*)&ew2[32768 + k * 128 + n2 * 2];
        float4 hv = *(const float4*)&hAT[k * 20 + e0];
        float he[4] = {hv.x, hv.y, hv.z, hv.w};
        #pragma unroll
        for (int e = 0; e < 4; e++) {
            float wx = (ae[e] == 0) ? w0.x : ((ae[e] == 1) ? w1.x : w2.x);
            float wy = (ae[e] == 0) ? w0.y : ((ae[e] == 1) ? w1.y : w2.y);
            acc[e][0] = fmaf(he[e], wx, acc[e][0]);
            acc[e][1] = fmaf(he[e], wy, acc[e][1]);
        }
    }
    #pragma unroll
    for (int e = 0; e < 4; e++)
        #pragma unroll
        for (int d = 0; d < 2; d++)
            hBT[(n2 * 2 + d) * 20 + e0 + e] = acc[e][d] + eb2[ae[e] * 128 + n2 * 2 + d];
    __syncthreads();

    // selection layer 3: 128 -> 10, write final output
    for (int idx = tid; idx < 160; idx += 256) {
        int e = idx / 10, o = idx - e * 10;
        int a = acts[e];
        float s = eb3[a * 10 + o];
        const float* w3 = &ew3[a * 1280];
        for (int k = 0; k < 128; k++) s = fmaf(hBT[k * 20 + e], w3[k * 10 + o], s);
        out[(img0 + e) * 10 + o] = s;
    }
}

// ---------------------------------------------------------------------------
extern "C" void kernel_launch(void* const* d_in, const int* in_sizes, int n_in,
                              void* d_out, int out_size, void* d_ws, size_t ws_size,
                              hipStream_t stream)
{
    const float* x   = (const float*)d_in[0];
    const float* cw1 = (const float*)d_in[1];
    const float* cb1 = (const float*)d_in[2];
    const float* cw2 = (const float*)d_in[3];
    const float* cb2 = (const float*)d_in[4];
    const float* cw3 = (const float*)d_in[5];
    const float* cb3 = (const float*)d_in[6];
    const float* bng = (const float*)d_in[7];
    const float* bnb = (const float*)d_in[8];
    const float* pw1 = (const float*)d_in[9];
    const float* pb1 = (const float*)d_in[10];
    const float* pw2 = (const float*)d_in[11];
    const float* pb2 = (const float*)d_in[12];
    const float* pw3 = (const float*)d_in[13];
    const float* pb3 = (const float*)d_in[14];
    const float* ew1 = (const float*)d_in[15];
    const float* eb1 = (const float*)d_in[16];
    const float* ew2 = (const float*)d_in[17];
    const float* eb2 = (const float*)d_in[18];
    const float* ew3 = (const float*)d_in[19];
    const float* eb3 = (const float*)d_in[20];

    float* out     = (float*)d_out;
    float* out3    = (float*)d_ws;                    // 4096*288
    float* pS      = out3 + 4096 * 288;               // 2048
    float* pSS     = pS + 2048;                       // 2048
    float* stats   = pSS + 2048;                      // 64
    float* packed2 = stats + 64;                      // 9216
    float* packed3 = packed2 + 9216;                  // 9216

    repack_kernel<<<72, 256, 0, stream>>>(cw2, cw3, packed2, packed3);
    fused_conv_kernel<<<4096, 512, 0, stream>>>(x, cw1, cb1, packed2, cb2, packed3, cb3, out3);
    bn_part_kernel<<<64, 256, 0, stream>>>(out3, pS, pSS);
    bn_final_kernel<<<1, 64, 0, stream>>>(pS, pSS, bng, bnb, stats);
    mlp_select_kernel<<<256, 256, 0, stream>>>(out3, stats,
                                               pw1, pb1, pw2, pb2, pw3, pb3,
                                               ew1, eb1, ew2, eb2, ew3, eb3, out);
}

// Round 5
// 527.754 us; speedup vs baseline: 7.5048x; 1.1210x over previous
//
#include <hip/hip_runtime.h>

// ---------------------------------------------------------------------------
// Kernel 0: repack conv2/conv3 weights from [oc][ic][tap] into chunk-linear
// [ch][rem=ld*9+tap][oc] so the fused kernel can stage coalesced+linear.
// ---------------------------------------------------------------------------
__global__ __launch_bounds__(256) void repack_kernel(
    const float* __restrict__ cw2, const float* __restrict__ cw3,
    float* __restrict__ packed2, float* __restrict__ packed3)
{
    int t = blockIdx.x * 256 + threadIdx.x;   // grid 72*256 = 18432 = 2*9216
    if (t < 9216) {
        int oc = t & 31, r = t >> 5;          // r = ch*72 + rem in [0,288)
        packed2[t] = cw2[oc * 288 + r];
    } else {
        int t2 = t - 9216;
        int oc = t2 & 31, r = t2 >> 5;
        packed3[t2] = cw3[oc * 288 + r];
    }
}

// ---------------------------------------------------------------------------
// Kernel 1: fused conv1+pool -> conv2+pool -> conv3+pool, one image per block.
// waves_per_eu pinned to (4,4): VGPR budget 128 (demand ~100) -> no spill,
// 2 blocks/CU (LDS 67 KB <= 80 KB).
// xs2: row stride 20, plane stride 324 -> conv2 patch reads conflict-free.
// xs3: row stride 10 (even) -> b64 patch reads in conv3.
// conv2: thread = 4oc x 14 prepool cols, K-split-4; pooling via register
// exchange (odd-R writes 28 floats, even-R combines).
// conv3: K-split-4, 4oc x (2x2 prepool), float4 weights + b64 patches.
// ---------------------------------------------------------------------------
__global__ __launch_bounds__(512)
__attribute__((amdgpu_waves_per_eu(4, 4)))
void fused_conv_kernel(
    const float* __restrict__ x,
    const float* __restrict__ cw1, const float* __restrict__ cb1,
    const float* __restrict__ packed2, const float* __restrict__ cb2,
    const float* __restrict__ packed3, const float* __restrict__ cb3,
    float* __restrict__ out3)
{
    const int img = blockIdx.x;
    const int tid = threadIdx.x;

    __shared__ float xs1[900];        // 30x30 zero-padded input image
    __shared__ float w1s[288];        // conv1 weights [tap][oc]
    __shared__ float b1s[32], b2s[32], b3s[32];
    __shared__ float xs2[32 * 324];   // conv2 in: 16 rows x stride 20, plane 324; also scratch
    __shared__ float wck[2304];       // 8-dic weight chunk [ld*9+tap][oc32]
    __shared__ float xs3[32 * 90];    // conv3 in: 9 rows x stride 10, padded

    // --- zero LDS (borders stay zero = implicit padding) ---
    for (int i = tid; i < 900;      i += 512) xs1[i] = 0.f;
    for (int i = tid; i < 32 * 324; i += 512) xs2[i] = 0.f;
    for (int i = tid; i < 32 * 90;  i += 512) xs3[i] = 0.f;
    __syncthreads();

    // --- stage input image + conv1 weights ---
    for (int i = tid; i < 784; i += 512) {
        int yy = i / 28, xx = i % 28;
        xs1[(yy + 1) * 30 + xx + 1] = x[img * 784 + i];
    }
    for (int i = tid; i < 288; i += 512) {
        int oc = i & 31, tap = i >> 5;
        w1s[i] = cw1[oc * 9 + tap];
    }
    if (tid < 32) { b1s[tid] = cb1[tid]; b2s[tid] = cb2[tid]; b3s[tid] = cb3[tid]; }
    __syncthreads();

    // --- conv1 (1->32) + relu + pool -> xs2 interior rows 1..14, cols 1..14 ---
    {
        const int c1 = tid & 31;                  // constant across o-iters
        float w1r[9];
        #pragma unroll
        for (int t = 0; t < 9; t++) w1r[t] = w1s[t * 32 + c1];   // lane-distinct banks
        const float bias1 = b1s[c1];
        for (int o = tid; o < 32 * 196; o += 512) {
            int p = o >> 5;
            int py = p / 14, px = p % 14;
            int base = (2 * py) * 30 + 2 * px;    // even -> b64 aligned
            float P[16];
            #pragma unroll
            for (int r = 0; r < 4; r++) {
                float2 u0 = *(const float2*)&xs1[base + r * 30];
                float2 u1 = *(const float2*)&xs1[base + r * 30 + 2];
                P[r * 4 + 0] = u0.x; P[r * 4 + 1] = u0.y;
                P[r * 4 + 2] = u1.x; P[r * 4 + 3] = u1.y;
            }
            float a00 = 0.f, a01 = 0.f, a10 = 0.f, a11 = 0.f;
            #pragma unroll
            for (int ky = 0; ky < 3; ky++)
                #pragma unroll
                for (int kx = 0; kx < 3; kx++) {
                    float w = w1r[ky * 3 + kx];
                    a00 = fmaf(P[ky * 4 + kx],           w, a00);
                    a01 = fmaf(P[ky * 4 + kx + 1],       w, a01);
                    a10 = fmaf(P[(ky + 1) * 4 + kx],     w, a10);
                    a11 = fmaf(P[(ky + 1) * 4 + kx + 1], w, a11);
                }
            float v = fmaxf(fmaxf(fmaxf(a00, a01), fmaxf(a10, a11)) + bias1, 0.f);
            xs2[c1 * 324 + (py + 1) * 20 + (px + 1)] = v;
        }
    }

    // --- conv2: 4oc x 14 prepool cols, K-split-4 over 4 chunks of 8 dic ---
    const int g  = tid >> 7;            // K-group 0..3 (2 waves each)
    const int u  = tid & 127;           // unit; active if u < 112
    const int cb = u & 7, R = u >> 3;   // oc-quad, prepool row 0..13
    const int oc0 = cb * 4;
    const bool act2 = (u < 112);

    float acc[4][14];
    #pragma unroll
    for (int a = 0; a < 4; a++)
        #pragma unroll
        for (int c = 0; c < 14; c++) acc[a][c] = 0.f;

    float pf[5];
    #pragma unroll
    for (int k = 0; k < 5; k++) {
        int idx = tid + k * 512;
        pf[k] = (idx < 2304) ? packed2[idx] : 0.f;
    }

    for (int ch = 0; ch < 4; ch++) {
        __syncthreads();                          // conv1/xs2 writes + prior wck reads done
        #pragma unroll
        for (int k = 0; k < 5; k++) {
            int idx = tid + k * 512;
            if (idx < 2304) wck[idx] = pf[k];
        }
        if (ch < 3) {
            #pragma unroll
            for (int k = 0; k < 5; k++) {
                int idx = tid + k * 512;
                pf[k] = (idx < 2304) ? packed2[(ch + 1) * 2304 + idx] : 0.f;
            }
        }
        __syncthreads();
        if (act2) {
            #pragma unroll
            for (int d = 0; d < 2; d++) {
                const int ld = 2 * g + d;
                const int ic = ch * 8 + ld;
                const float* wd = &wck[ld * 288 + oc0];
                const int pb = ic * 324;
                #pragma unroll
                for (int ky = 0; ky < 3; ky++) {
                    const int rb = pb + (R + ky) * 20;   // banks 20*(R+ky)%32 distinct
                    float row[16];
                    #pragma unroll
                    for (int q = 0; q < 4; q++) {
                        const float4 t = *(const float4*)&xs2[rb + q * 4];
                        row[q * 4 + 0] = t.x; row[q * 4 + 1] = t.y;
                        row[q * 4 + 2] = t.z; row[q * 4 + 3] = t.w;
                    }
                    const float4 wa = *(const float4*)&wd[(ky * 3 + 0) * 32];
                    const float4 wb = *(const float4*)&wd[(ky * 3 + 1) * 32];
                    const float4 wc = *(const float4*)&wd[(ky * 3 + 2) * 32];
                    #pragma unroll
                    for (int c = 0; c < 14; c++) {
                        acc[0][c] = fmaf(row[c],     wa.x, acc[0][c]);
                        acc[1][c] = fmaf(row[c],     wa.y, acc[1][c]);
                        acc[2][c] = fmaf(row[c],     wa.z, acc[2][c]);
                        acc[3][c] = fmaf(row[c],     wa.w, acc[3][c]);
                        acc[0][c] = fmaf(row[c + 1], wb.x, acc[0][c]);
                        acc[1][c] = fmaf(row[c + 1], wb.y, acc[1][c]);
                        acc[2][c] = fmaf(row[c + 1], wb.z, acc[2][c]);
                        acc[3][c] = fmaf(row[c + 1], wb.w, acc[3][c]);
                        acc[0][c] = fmaf(row[c + 2], wc.x, acc[0][c]);
                        acc[1][c] = fmaf(row[c + 2], wc.y, acc[1][c]);
                        acc[2][c] = fmaf(row[c + 2], wc.z, acc[2][c]);
                        acc[3][c] = fmaf(row[c + 2], wc.w, acc[3][c]);
                    }
                }
            }
        }
    }

    // --- conv2 K-reduction (3 rounds), scratch overlays xs2 (stride 57) ---
    float* sc = xs2;
    __syncthreads();                               // all xs2 patch reads done
    for (int s = 1; s < 4; s++) {
        if (g == s && act2) {
            #pragma unroll
            for (int a = 0; a < 4; a++)
                #pragma unroll
                for (int c = 0; c < 14; c++) sc[u * 57 + a * 14 + c] = acc[a][c];
        }
        __syncthreads();
        if (g == 0 && act2) {
            #pragma unroll
            for (int a = 0; a < 4; a++)
                #pragma unroll
                for (int c = 0; c < 14; c++) acc[a][c] += sc[u * 57 + a * 14 + c];
        }
        __syncthreads();
    }

    // --- pool 14x14 -> 7x7 in registers: horizontal max, odd/even R exchange ---
    float hm[4][7];
    if (g == 0 && act2) {
        #pragma unroll
        for (int a = 0; a < 4; a++)
            #pragma unroll
            for (int c = 0; c < 7; c++)
                hm[a][c] = fmaxf(acc[a][2 * c], acc[a][2 * c + 1]);
        if (R & 1) {
            #pragma unroll
            for (int a = 0; a < 4; a++)
                #pragma unroll
                for (int c = 0; c < 7; c++) sc[u * 29 + a * 7 + c] = hm[a][c];
        }
    }
    __syncthreads();
    if (g == 0 && act2 && !(R & 1)) {
        const int py = R >> 1;                     // 0..6
        #pragma unroll
        for (int a = 0; a < 4; a++)
            #pragma unroll
            for (int c = 0; c < 7; c++) {
                float v = fmaxf(hm[a][c], sc[(u + 8) * 29 + a * 7 + c]);
                v = fmaxf(v + b2s[oc0 + a], 0.f);
                xs3[(oc0 + a) * 90 + (py + 1) * 10 + (c + 1)] = v;
            }
    }

    // --- conv3 (32->32, 7x7) + relu + pool(7->3 floor), K-split-4 ---
    const int u3 = tid & 127;
    const bool act3 = (u3 < 72);
    const int cq3 = u3 & 7, pos = u3 >> 3;        // oc-quad, pooled pos 0..8
    const int oc30 = cq3 * 4;
    const int py3 = pos / 3, px3 = pos % 3;
    const int base3 = (2 * py3) * 10 + 2 * px3;   // even -> b64 aligned

    float a3[4][4];
    #pragma unroll
    for (int a = 0; a < 4; a++)
        #pragma unroll
        for (int q = 0; q < 4; q++) a3[a][q] = 0.f;

    float pg[5];
    #pragma unroll
    for (int k = 0; k < 5; k++) {
        int idx = tid + k * 512;
        pg[k] = (idx < 2304) ? packed3[idx] : 0.f;
    }

    for (int ch = 0; ch < 4; ch++) {
        __syncthreads();                           // xs3 writes / prior wck reads done
        #pragma unroll
        for (int k = 0; k < 5; k++) {
            int idx = tid + k * 512;
            if (idx < 2304) wck[idx] = pg[k];
        }
        if (ch < 3) {
            #pragma unroll
            for (int k = 0; k < 5; k++) {
                int idx = tid + k * 512;
                pg[k] = (idx < 2304) ? packed3[(ch + 1) * 2304 + idx] : 0.f;
            }
        }
        __syncthreads();
        if (act3) {
            #pragma unroll
            for (int d = 0; d < 2; d++) {
                const int ld = 2 * g + d;
                const int ic = ch * 8 + ld;
                const float* xp = &xs3[ic * 90 + base3];
                float P[16];
                #pragma unroll
                for (int r = 0; r < 4; r++) {
                    float2 u0 = *(const float2*)&xp[r * 10];
                    float2 u1 = *(const float2*)&xp[r * 10 + 2];
                    P[r * 4 + 0] = u0.x; P[r * 4 + 1] = u0.y;
                    P[r * 4 + 2] = u1.x; P[r * 4 + 3] = u1.y;
                }
                const float* wd = &wck[ld * 288 + oc30];
                #pragma unroll
                for (int tap = 0; tap < 9; tap++) {
                    const int ky = tap / 3, kx = tap % 3;
                    const float4 wv = *(const float4*)&wd[tap * 32];
                    const float x00 = P[ky * 4 + kx];
                    const float x01 = P[ky * 4 + kx + 1];
                    const float x10 = P[(ky + 1) * 4 + kx];
                    const float x11 = P[(ky + 1) * 4 + kx + 1];
                    a3[0][0] = fmaf(x00, wv.x, a3[0][0]); a3[0][1] = fmaf(x01, wv.x, a3[0][1]);
                    a3[0][2] = fmaf(x10, wv.x, a3[0][2]); a3[0][3] = fmaf(x11, wv.x, a3[0][3]);
                    a3[1][0] = fmaf(x00, wv.y, a3[1][0]); a3[1][1] = fmaf(x01, wv.y, a3[1][1]);
                    a3[1][2] = fmaf(x10, wv.y, a3[1][2]); a3[1][3] = fmaf(x11, wv.y, a3[1][3]);
                    a3[2][0] = fmaf(x00, wv.z, a3[2][0]); a3[2][1] = fmaf(x01, wv.z, a3[2][1]);
                    a3[2][2] = fmaf(x10, wv.z, a3[2][2]); a3[2][3] = fmaf(x11, wv.z, a3[2][3]);
                    a3[3][0] = fmaf(x00, wv.w, a3[3][0]); a3[3][1] = fmaf(x01, wv.w, a3[3][1]);
                    a3[3][2] = fmaf(x10, wv.w, a3[3][2]); a3[3][3] = fmaf(x11, wv.w, a3[3][3]);
                }
            }
        }
    }

    // --- conv3 K-reduction (3 rounds, stride-17 scratch in xs2 region) ---
    __syncthreads();
    for (int s = 1; s < 4; s++) {
        if (g == s && act3) {
            #pragma unroll
            for (int a = 0; a < 4; a++)
                #pragma unroll
                for (int q = 0; q < 4; q++) sc[u3 * 17 + a * 4 + q] = a3[a][q];
        }
        __syncthreads();
        if (g == 0 && act3) {
            #pragma unroll
            for (int a = 0; a < 4; a++)
                #pragma unroll
                for (int q = 0; q < 4; q++) a3[a][q] += sc[u3 * 17 + a * 4 + q];
        }
        __syncthreads();
    }
    if (g == 0 && act3) {
        float4 res;
        float* r = (float*)&res;
        #pragma unroll
        for (int a = 0; a < 4; a++) {
            float v = fmaxf(fmaxf(a3[a][0], a3[a][1]), fmaxf(a3[a][2], a3[a][3]));
            r[a] = fmaxf(v + b3s[oc30 + a], 0.f);
        }
        *(float4*)&out3[img * 288 + pos * 32 + oc30] = res;
    }
}

// ---------------------------------------------------------------------------
// Kernel 2a/2b: BatchNorm stats, two-stage
// ---------------------------------------------------------------------------
__global__ __launch_bounds__(256) void bn_part_kernel(
    const float* __restrict__ out3, float* __restrict__ pS, float* __restrict__ pSS)
{
    const int blk = blockIdx.x;                   // 64 blocks
    const int c = threadIdx.x & 31, ml = threadIdx.x >> 5;
    float s = 0.f, ss = 0.f;
    const int base = blk * 576 + ml;
    for (int k = 0; k < 72; k++) {
        float v = out3[(base + k * 8) * 32 + c];  // coalesced
        s += v; ss = fmaf(v, v, ss);
    }
    __shared__ float rs[256], rss[256];
    rs[threadIdx.x] = s; rss[threadIdx.x] = ss;
    __syncthreads();
    if (threadIdx.x < 32) {
        float S = 0.f, SS = 0.f;
        #pragma unroll
        for (int m = 0; m < 8; m++) { S += rs[threadIdx.x + 32 * m]; SS += rss[threadIdx.x + 32 * m]; }
        pS[blk * 32 + threadIdx.x] = S;
        pSS[blk * 32 + threadIdx.x] = SS;
    }
}

__global__ __launch_bounds__(64) void bn_final_kernel(
    const float* __restrict__ pS, const float* __restrict__ pSS,
    const float* __restrict__ bng, const float* __restrict__ bnb,
    float* __restrict__ stats)
{
    int c = threadIdx.x;
    if (c < 32) {
        float S = 0.f, SS = 0.f;
        for (int b = 0; b < 64; b++) { S += pS[b * 32 + c]; SS += pSS[b * 32 + c]; }
        const float inv_n = 1.f / (4096.f * 9.f);
        float mean = S * inv_n;
        float var = SS * inv_n - mean * mean;
        float a = bng[c] * rsqrtf(var + 1e-5f);
        stats[c] = a;
        stats[32 + c] = bnb[c] - a * mean;
    }
}

// ---------------------------------------------------------------------------
// Kernel 3: BN-apply + MLP + argmax + 3 selection layers. (round-3 version)
// ---------------------------------------------------------------------------
__global__ __launch_bounds__(256) void mlp_select_kernel(
    const float* __restrict__ out3, const float* __restrict__ stats,
    const float* __restrict__ pw1, const float* __restrict__ pb1,
    const float* __restrict__ pw2, const float* __restrict__ pb2,
    const float* __restrict__ pw3, const float* __restrict__ pb3,
    const float* __restrict__ ew1, const float* __restrict__ eb1,
    const float* __restrict__ ew2, const float* __restrict__ eb2,
    const float* __restrict__ ew3, const float* __restrict__ eb3,
    float* __restrict__ out)
{
    const int tid = threadIdx.x;
    const int img0 = blockIdx.x * 16;

    __shared__ float ysT[288 * 20];   // [j][e], stride 20
    __shared__ float hAT[128 * 20];
    __shared__ float hBT[128 * 20];
    __shared__ float lg[48];
    __shared__ int   acts[16];
    __shared__ float sa[32], sb[32];

    if (tid < 32) { sa[tid] = stats[tid]; sb[tid] = stats[32 + tid]; }
    __syncthreads();

    for (int it = 0; it < 5; it++) {
        int i4 = it * 256 + tid;
        if (i4 < 1152) {
            int e = i4 / 72, jq = i4 - e * 72;
            float4 v = *(const float4*)&out3[(img0 + e) * 288 + jq * 4];
            int j = jq * 4;
            ysT[(j + 0) * 20 + e] = fmaf(sa[(j + 0) & 31], v.x, sb[(j + 0) & 31]);
            ysT[(j + 1) * 20 + e] = fmaf(sa[(j + 1) & 31], v.y, sb[(j + 1) & 31]);
            ysT[(j + 2) * 20 + e] = fmaf(sa[(j + 2) & 31], v.z, sb[(j + 2) & 31]);
            ysT[(j + 3) * 20 + e] = fmaf(sa[(j + 3) & 31], v.w, sb[(j + 3) & 31]);
        }
    }
    __syncthreads();

    const int n2 = tid & 63, eT = tid >> 6, e0 = eT * 4;
    float acc[4][2];

    #pragma unroll
    for (int e = 0; e < 4; e++) { acc[e][0] = pb1[n2 * 2]; acc[e][1] = pb1[n2 * 2 + 1]; }
    for (int k = 0; k < 288; k++) {
        int i = (k & 31) * 9 + (k >> 5);
        float2 w = *(const float2*)&pw1[i * 128 + n2 * 2];
        float4 yv = *(const float4*)&ysT[k * 20 + e0];
        acc[0][0] = fmaf(yv.x, w.x, acc[0][0]); acc[0][1] = fmaf(yv.x, w.y, acc[0][1]);
        acc[1][0] = fmaf(yv.y, w.x, acc[1][0]); acc[1][1] = fmaf(yv.y, w.y, acc[1][1]);
        acc[2][0] = fmaf(yv.z, w.x, acc[2][0]); acc[2][1] = fmaf(yv.z, w.y, acc[2][1]);
        acc[3][0] = fmaf(yv.w, w.x, acc[3][0]); acc[3][1] = fmaf(yv.w, w.y, acc[3][1]);
    }
    #pragma unroll
    for (int e = 0; e < 4; e++)
        #pragma unroll
        for (int d = 0; d < 2; d++)
            hAT[(n2 * 2 + d) * 20 + e0 + e] = fmaxf(acc[e][d], 0.f);
    __syncthreads();

    #pragma unroll
    for (int e = 0; e < 4; e++) { acc[e][0] = pb2[n2 * 2]; acc[e][1] = pb2[n2 * 2 + 1]; }
    for (int k = 0; k < 128; k++) {
        float2 w = *(const float2*)&pw2[k * 128 + n2 * 2];
        float4 hv = *(const float4*)&hAT[k * 20 + e0];
        acc[0][0] = fmaf(hv.x, w.x, acc[0][0]); acc[0][1] = fmaf(hv.x, w.y, acc[0][1]);
        acc[1][0] = fmaf(hv.y, w.x, acc[1][0]); acc[1][1] = fmaf(hv.y, w.y, acc[1][1]);
        acc[2][0] = fmaf(hv.z, w.x, acc[2][0]); acc[2][1] = fmaf(hv.z, w.y, acc[2][1]);
        acc[3][0] = fmaf(hv.w, w.x, acc[3][0]); acc[3][1] = fmaf(hv.w, w.y, acc[3][1]);
    }
    #pragma unroll
    for (int e = 0; e < 4; e++)
        #pragma unroll
        for (int d = 0; d < 2; d++)
            hBT[(n2 * 2 + d) * 20 + e0 + e] = fmaxf(acc[e][d], 0.f);
    __syncthreads();

    if (tid < 48) {
        int e = tid / 3, o = tid - e * 3;
        float s = pb3[o];
        for (int k = 0; k < 128; k++) s = fmaf(hBT[k * 20 + e], pw3[k * 3 + o], s);
        lg[e * 3 + o] = s;
    }
    __syncthreads();
    if (tid < 16) {
        float l0 = lg[tid * 3], l1 = lg[tid * 3 + 1], l2 = lg[tid * 3 + 2];
        int a = 0; float best = l0;
        if (l1 > best) { best = l1; a = 1; }
        if (l2 > best) { best = l2; a = 2; }
        acts[tid] = a;
        out[4096 * 10 + img0 + tid] = (float)a;
    }
    __syncthreads();

    int ae[4];
    #pragma unroll
    for (int e = 0; e < 4; e++) ae[e] = acts[e0 + e];

    #pragma unroll
    for (int e = 0; e < 4; e++) { acc[e][0] = 0.f; acc[e][1] = 0.f; }
    for (int k = 0; k < 288; k++) {
        int i = (k & 31) * 9 + (k >> 5);
        float2 w0 = *(const float2*)&ew1[i * 128 + n2 * 2];
        float2 w1 = *(const float2*)&ew1[36864 + i * 128 + n2 * 2];
        float2 w2 = *(const float2*)&ew1[73728 + i * 128 + n2 * 2];
        float4 yv = *(const float4*)&ysT[k * 20 + e0];
        float ye[4] = {yv.x, yv.y, yv.z, yv.w};
        #pragma unroll
        for (int e = 0; e < 4; e++) {
            float wx = (ae[e] == 0) ? w0.x : ((ae[e] == 1) ? w1.x : w2.x);
            float wy = (ae[e] == 0) ? w0.y : ((ae[e] == 1) ? w1.y : w2.y);
            acc[e][0] = fmaf(ye[e], wx, acc[e][0]);
            acc[e][1] = fmaf(ye[e], wy, acc[e][1]);
        }
    }
    #pragma unroll
    for (int e = 0; e < 4; e++)
        #pragma unroll
        for (int d = 0; d < 2; d++)
            hAT[(n2 * 2 + d) * 20 + e0 + e] = acc[e][d] + eb1[ae[e] * 128 + n2 * 2 + d];
    __syncthreads();

    #pragma unroll
    for (int e = 0; e < 4; e++) { acc[e][0] = 0.f; acc[e][1] = 0.f; }
    for (int k = 0; k < 128; k++) {
        float2 w0 = *(const float2*)&ew2[k * 128 + n2 * 2];
        float2 w1 = *(const float2*)&ew2[16384 + k * 128 + n2 * 2];
        float2 w2 = *(const float2*)&ew2[32768 + k * 128 + n2 * 2];
        float4 hv = *(const float4*)&hAT[k * 20 + e0];
        float he[4] = {hv.x, hv.y, hv.z, hv.w};
        #pragma unroll
        for (int e = 0; e < 4; e++) {
            float wx = (ae[e] == 0) ? w0.x : ((ae[e] == 1) ? w1.x : w2.x);
            float wy = (ae[e] == 0) ? w0.y : ((ae[e] == 1) ? w1.y : w2.y);
            acc[e][0] = fmaf(he[e], wx, acc[e][0]);
            acc[e][1] = fmaf(he[e], wy, acc[e][1]);
        }
    }
    #pragma unroll
    for (int e = 0; e < 4; e++)
        #pragma unroll
        for (int d = 0; d < 2; d++)
            hBT[(n2 * 2 + d) * 20 + e0 + e] = acc[e][d] + eb2[ae[e] * 128 + n2 * 2 + d];
    __syncthreads();

    for (int idx = tid; idx < 160; idx += 256) {
        int e = idx / 10, o = idx - e * 10;
        int a = acts[e];
        float s = eb3[a * 10 + o];
        const float* w3 = &ew3[a * 1280];
        for (int k = 0; k < 128; k++) s = fmaf(hBT[k * 20 + e], w3[k * 10 + o], s);
        out[(img0 + e) * 10 + o] = s;
    }
}

// ---------------------------------------------------------------------------
extern "C" void kernel_launch(void* const* d_in, const int* in_sizes, int n_in,
                              void* d_out, int out_size, void* d_ws, size_t ws_size,
                              hipStream_t stream)
{
    const float* x   = (const float*)d_in[0];
    const float* cw1 = (const float*)d_in[1];
    const float* cb1 = (const float*)d_in[2];
    const float* cw2 = (const float*)d_in[3];
    const float* cb2 = (const float*)d_in[4];
    const float* cw3 = (const float*)d_in[5];
    const float* cb3 = (const float*)d_in[6];
    const float* bng = (const float*)d_in[7];
    const float* bnb = (const float*)d_in[8];
    const float* pw1 = (const float*)d_in[9];
    const float* pb1 = (const float*)d_in[10];
    const float* pw2 = (const float*)d_in[11];
    const float* pb2 = (const float*)d_in[12];
    const float* pw3 = (const float*)d_in[13];
    const float* pb3 = (const float*)d_in[14];
    const float* ew1 = (const float*)d_in[15];
    const float* eb1 = (const float*)d_in[16];
    const float* ew2 = (const float*)d_in[17];
    const float* eb2 = (const float*)d_in[18];
    const float* ew3 = (const float*)d_in[19];
    const float* eb3 = (const float*)d_in[20];

    float* out     = (float*)d_out;
    float* out3    = (float*)d_ws;                    // 4096*288
    float* pS      = out3 + 4096 * 288;               // 2048
    float* pSS     = pS + 2048;                       // 2048
    float* stats   = pSS + 2048;                      // 64
    float* packed2 = stats + 64;                      // 9216
    float* packed3 = packed2 + 9216;                  // 9216

    repack_kernel<<<72, 256, 0, stream>>>(cw2, cw3, packed2, packed3);
    fused_conv_kernel<<<4096, 512, 0, stream>>>(x, cw1, cb1, packed2, cb2, packed3, cb3, out3);
    bn_part_kernel<<<64, 256, 0, stream>>>(out3, pS, pSS);
    bn_final_kernel<<<1, 64, 0, stream>>>(pS, pSS, bng, bnb, stats);
    mlp_select_kernel<<<256, 256, 0, stream>>>(out3, stats,
                                               pw1, pb1, pw2, pb2, pw3, pb3,
                                               ew1, eb1, ew2, eb2, ew3, eb3, out);
}